// Round 6
// baseline (299.210 us; speedup 1.0000x reference)
//
#include <hip/hip_runtime.h>
#include <stdint.h>

typedef unsigned short u16;
typedef unsigned int   u32;
typedef __bf16 bf16_t;
typedef bf16_t bf16x8 __attribute__((ext_vector_type(8)));
typedef u16    u16x8  __attribute__((ext_vector_type(8)));
typedef float  f32x4  __attribute__((ext_vector_type(4)));
typedef float  f32x16 __attribute__((ext_vector_type(16)));

#define NB   2
#define NL   2048
#define ND   2048
#define NHQ  32
#define NHKV 8
#define NHD  64
#define NQKV 3072   // D + 2*HKV*HD
#define QSCALE 0.18033688011112042f   // 0.125 * log2(e): softmax runs in exp2 domain

__device__ __forceinline__ u16 f2bf(float x){
  union{float f;u32 u;} v; v.f = x;
  u32 r = v.u + 0x7FFFu + ((v.u >> 16) & 1u);   // RTNE
  return (u16)(r >> 16);
}
__device__ __forceinline__ float bf2f(u16 b){
  union{u32 u;float f;} v; v.u = ((u32)b) << 16; return v.f;
}

__device__ __forceinline__ float exp2_hw(float x){
#if __has_builtin(__builtin_amdgcn_exp2f)
  return __builtin_amdgcn_exp2f(x);
#else
  float r; asm("v_exp_f32 %0, %1" : "=v"(r) : "v"(x)); return r;
#endif
}

__device__ __forceinline__ void gload_lds16(const void* g, void* l){
  auto gp = reinterpret_cast<__attribute__((address_space(1))) u16*>(
      (uintptr_t)g);
  auto lp = reinterpret_cast<__attribute__((address_space(3))) u16*>(
      (uintptr_t)l);
  __builtin_amdgcn_global_load_lds(gp, lp, 16, 0, 0);
}

__device__ __forceinline__ f32x4 mfma16(bf16x8 a, bf16x8 b, f32x4 c){
  return __builtin_amdgcn_mfma_f32_16x16x32_bf16(a, b, c, 0, 0, 0);
}
__device__ __forceinline__ f32x16 mfma32(bf16x8 a, bf16x8 b, f32x16 c){
  return __builtin_amdgcn_mfma_f32_32x32x16_bf16(a, b, c, 0, 0, 0);
}
__device__ __forceinline__ u32 cvtpk(float lo, float hi){
  u32 w;
  asm("v_cvt_pk_bf16_f32 %0, %1, %2" : "=v"(w) : "v"(lo), "v"(hi));
  return w;
}

// ---------------- fp32 -> bf16 convert (vectorized) ----------------
__global__ void k_cvt(const float* __restrict__ in, u16* __restrict__ out, int n4){
  int i = blockIdx.x * blockDim.x + threadIdx.x;
  if (i >= n4) return;
  float4 f = reinterpret_cast<const float4*>(in)[i];
  ushort4 o;
  o.x = f2bf(f.x); o.y = f2bf(f.y); o.z = f2bf(f.z); o.w = f2bf(f.w);
  reinterpret_cast<ushort4*>(out)[i] = o;
}

// ---------------- RoPE cos/sin table [L][32] ----------------
__global__ void k_rope_tab(const int* __restrict__ pos, float* __restrict__ cosT,
                           float* __restrict__ sinT){
  int idx = blockIdx.x * 256 + threadIdx.x;      // 65536 total
  int l = idx >> 5, i = idx & 31;
  float p = (float)pos[l];
  float inv = __expf(-((float)i * (1.0f/32.0f)) * 9.210340371976184f); // ln(1e4)
  float fr = p * inv;
  cosT[idx] = cosf(fr);
  sinT[idx] = sinf(fr);
}

// ---------------- bf16 NT GEMM: C[M][N] = A[M][K] * B[N][K]^T ----------------
template<int WRITE_F32>
__global__ __launch_bounds__(256) void k_gemm_nt(const u16* __restrict__ A,
                                                 const u16* __restrict__ Bm,
                                                 void* __restrict__ Cp,
                                                 int M, int N, int K){
  __shared__ u16 As[128*32];
  __shared__ u16 Bs[128*32];
  const int tid = threadIdx.x;
  const int lane = tid & 63;
  const int w = tid >> 6;
  const int wr = w >> 1, wc = w & 1;
  const int tm = blockIdx.y * 128, tn = blockIdx.x * 128;
  const int lr = lane & 15, lg = lane >> 4;

  const int ca = 2*w, cb = 2*w+1;
  const u16* pa0 = A  + (size_t)(tm + ca*16 + (lane>>2))*K + (lane&3)*8;
  const u16* pa1 = A  + (size_t)(tm + cb*16 + (lane>>2))*K + (lane&3)*8;
  const u16* pb0 = Bm + (size_t)(tn + ca*16 + (lane>>2))*K + (lane&3)*8;
  const u16* pb1 = Bm + (size_t)(tn + cb*16 + (lane>>2))*K + (lane&3)*8;
  u16* la0 = &As[ca*512];
  u16* la1 = &As[cb*512];
  u16* lb0 = &Bs[ca*512];
  u16* lb1 = &Bs[cb*512];

  f32x4 acc[4][4] = {};

  const int nk = K >> 5;
  for (int kt = 0; kt < nk; ++kt){
    gload_lds16(pa0, la0);
    gload_lds16(pa1, la1);
    gload_lds16(pb0, lb0);
    gload_lds16(pb1, lb1);
    pa0 += 32; pa1 += 32; pb0 += 32; pb1 += 32;
    __syncthreads();
    bf16x8 af[4], bfr[4];
#pragma unroll
    for (int m = 0; m < 4; ++m)
      af[m] = *reinterpret_cast<const bf16x8*>(&As[(wr*64 + m*16 + lr)*32 + lg*8]);
#pragma unroll
    for (int n = 0; n < 4; ++n)
      bfr[n] = *reinterpret_cast<const bf16x8*>(&Bs[(wc*64 + n*16 + lr)*32 + lg*8]);
#pragma unroll
    for (int m = 0; m < 4; ++m)
#pragma unroll
      for (int n = 0; n < 4; ++n)
        acc[m][n] = mfma16(af[m], bfr[n], acc[m][n]);
    __syncthreads();
  }

  const int rbase = tm + wr*64 + lg*4;
  const int cbase = tn + wc*64 + lr;
#pragma unroll
  for (int m = 0; m < 4; ++m){
#pragma unroll
    for (int n = 0; n < 4; ++n){
#pragma unroll
      for (int r = 0; r < 4; ++r){
        size_t off = (size_t)(rbase + m*16 + r)*N + (cbase + n*16);
        if (WRITE_F32) ((float*)Cp)[off] = acc[m][n][r];
        else           ((u16*)Cp)[off]   = f2bf(acc[m][n][r]);
      }
    }
  }
}

// ---------------- RoPE + scatter ----------------
__global__ void k_rope_scatter(const u16* __restrict__ qkv, const float* __restrict__ cosT,
                               const float* __restrict__ sinT,
                               u16* __restrict__ Q, u16* __restrict__ Ko, u16* __restrict__ V){
  const int row = blockIdx.x;                 // b*L + l
  const int b = row >> 11, l = row & 2047;
  const int t = threadIdx.x;
#pragma unroll
  for (int it = 0; it < 6; ++it){
    int pp = t + it*256;
    u32 xin = *reinterpret_cast<const u32*>(&qkv[(size_t)row*NQKV + pp*2]);
    float x1 = bf2f((u16)(xin & 0xFFFFu));
    float x2 = bf2f((u16)(xin >> 16));
    if (pp < 1280){
      int i = pp & 31;
      float c = cosT[l*32 + i], s = sinT[l*32 + i];
      float y1 = x1*c - x2*s;
      float y2 = x1*s + x2*c;
      if (pp < 1024){
        int hh = pp >> 5, d = (pp & 31)*2;
        u32 o = (u32)f2bf(y1*QSCALE) | ((u32)f2bf(y2*QSCALE) << 16);
        *reinterpret_cast<u32*>(&Q[(((size_t)(b*NHQ + hh))*NL + l)*NHD + d]) = o;
      } else {
        int idx = pp - 1024, kvh = idx >> 5, d = (idx & 31)*2;
        u32 o = (u32)f2bf(y1) | ((u32)f2bf(y2) << 16);
        *reinterpret_cast<u32*>(&Ko[(((size_t)(b*NHKV + kvh))*NL + l)*NHD + d]) = o;
      }
    } else {
      int idx = pp - 1280, kvh = idx >> 5, d = (idx & 31)*2;
      *reinterpret_cast<u32*>(&V[(((size_t)(b*NHKV + kvh))*NL + l)*NHD + d]) = xin;
    }
  }
}

// ---------------- V[b][kvh][l][d] -> VT[b][kvh][d][l] ----------------
__global__ __launch_bounds__(256) void k_transpose(const u16* __restrict__ V, u16* __restrict__ VT){
  __shared__ u16 T[64*72];
  const int bid = blockIdx.x;
  const int slice = bid >> 5, tile = bid & 31;
  const u16* src = V  + (size_t)slice*NL*NHD + (size_t)tile*64*NHD;
  u16*       dst = VT + (size_t)slice*NHD*NL + (size_t)tile*64;
  const int t = threadIdx.x;
  {
    int r = t >> 2, c0 = (t & 3)*16;
    const u16x8* s = reinterpret_cast<const u16x8*>(src + (size_t)r*NHD + c0);
    *reinterpret_cast<u16x8*>(&T[r*72 + c0])     = s[0];
    *reinterpret_cast<u16x8*>(&T[r*72 + c0 + 8]) = s[1];
  }
  __syncthreads();
  {
    int d = t >> 2, l0 = (t & 3)*16;
    u16x8 v0, v1;
#pragma unroll
    for (int j = 0; j < 8; ++j) v0[j] = T[(l0+j)*72 + d];
#pragma unroll
    for (int j = 0; j < 8; ++j) v1[j] = T[(l0+8+j)*72 + d];
    u16* dp = dst + (size_t)d*NL + l0;
    *reinterpret_cast<u16x8*>(dp)     = v0;
    *reinterpret_cast<u16x8*>(dp + 8) = v1;
  }
}

// ---------------- causal GQA flash attention: single-stream + pinned prefetch ----------------
// 1 wave = 1 q-tile (32 rows). 4096 wave-tasks, 1024 blocks. Causal balance
// within a block: waves get qt {k, 63-k, k+16, 47-k}.
// R5 lesson: without fences the scheduler SINKS prefetch loads to their use
// (VGPR 92 proves it) and every tile pays serial L2 latency. sched_barrier(0)
// at phase boundaries pins: K(j+1) issues before softmax(j); V(j+1) issues at
// tile end. Compiler then emits counted vmcnt (rolling [V(j),K(j+1)] queue).
// Plain launch_bounds(256): no occupancy clamp (R4: ",3" spilled; R5: ",2" capped).
__device__ __forceinline__ void load_kfrag(bf16x8 f[8], const u16* Kp, int kvb, int q32, int hi){
#pragma unroll
  for (int ks = 0; ks < 4; ++ks){
    f[ks]   = *reinterpret_cast<const bf16x8*>(&Kp[(size_t)(kvb + q32)*NHD      + ks*16 + hi*8]);
    f[4+ks] = *reinterpret_cast<const bf16x8*>(&Kp[(size_t)(kvb + 32 + q32)*NHD + ks*16 + hi*8]);
  }
}
__device__ __forceinline__ void load_vfrag(bf16x8 f[8], const u16* Vp, int kvb, int q32, int hi){
#pragma unroll
  for (int ks = 0; ks < 4; ++ks){
    f[ks]   = *reinterpret_cast<const bf16x8*>(&Vp[(size_t)(q32)*NL      + kvb + ks*16 + hi*8]);
    f[4+ks] = *reinterpret_cast<const bf16x8*>(&Vp[(size_t)(32 + q32)*NL + kvb + ks*16 + hi*8]);
  }
}

template<bool MASK, bool PRE>
__device__ __forceinline__ void attn_tile(
    f32x16& o0, f32x16& o1, float& mrun, float& lsum,
    const bf16x8 qf[4], const bf16x8 kf[8], bf16x8 kfn[8], bf16x8 vf[8],
    const u16* __restrict__ Kp, const u16* __restrict__ Vp,
    int kvb, int qrow, int q32, int hi)
{
  f32x16 s0 = {}, s1 = {};
  __builtin_amdgcn_s_setprio(1);
#pragma unroll
  for (int ks = 0; ks < 4; ++ks){
    s0 = mfma32(kf[ks],   qf[ks], s0);
    s1 = mfma32(kf[4+ks], qf[ks], s1);
  }
  __builtin_amdgcn_s_setprio(0);
  if (PRE) load_kfrag(kfn, Kp, kvb + 64, q32, hi);   // issue now...
  __builtin_amdgcn_sched_barrier(0);                  // ...and stay issued (no sinking)

  float pv[32];
#pragma unroll
  for (int r = 0; r < 16; ++r){ pv[r] = s0[r]; pv[16+r] = s1[r]; }
  if (MASK){
#pragma unroll
    for (int r = 0; r < 16; ++r){
      const int kl = (r&3) + 8*(r>>2) + 4*hi;
      pv[r]    = (kvb + kl      <= qrow) ? pv[r]    : -1e30f;
      pv[16+r] = (kvb + 32 + kl <= qrow) ? pv[16+r] : -1e30f;
    }
  }
  // row max: max3-shaped tree + one cross-half shuffle
  float t[8];
#pragma unroll
  for (int r = 0; r < 8; ++r)  t[r] = fmaxf(fmaxf(pv[r], pv[r+8]), pv[r+16]);
#pragma unroll
  for (int r = 0; r < 4; ++r)  t[r] = fmaxf(fmaxf(t[r], t[r+4]), pv[24+r]);
  t[0] = fmaxf(fmaxf(t[0], t[1]), fmaxf(t[2], t[3]));
  const float mnew = fmaxf(t[0], __shfl_xor(t[0], 32));
  if (__any(mnew - mrun > 8.0f)){              // defer-max (T13)
    const float mupd = fmaxf(mrun, mnew);
    const float c = exp2_hw(mrun - mupd);
    lsum *= c;
#pragma unroll
    for (int r = 0; r < 16; ++r){ o0[r] *= c; o1[r] *= c; }
    mrun = mupd;
  }
  float p[32];
#pragma unroll
  for (int r = 0; r < 32; ++r) p[r] = exp2_hw(pv[r] - mrun);
  float u[16];
#pragma unroll
  for (int r = 0; r < 16; ++r) u[r] = p[r] + p[16+r];
#pragma unroll
  for (int r = 0; r < 8; ++r)  u[r] += u[r+8];
#pragma unroll
  for (int r = 0; r < 4; ++r)  u[r] += u[r+4];
  lsum += (u[0]+u[1]) + (u[2]+u[3]);
  // P -> bf16 B-frags (cvt_pk + permlane32_swap, in-register)
  u32 wds[16];
#pragma unroll
  for (int i = 0; i < 16; ++i) wds[i] = cvtpk(p[2*i], p[2*i+1]);
  bf16x8 pf[4];
#pragma unroll
  for (int f = 0; f < 4; ++f){
    u32 x  = wds[4*f+0], y  = wds[4*f+2];
    u32 x2 = wds[4*f+1], y2 = wds[4*f+3];
    asm("v_permlane32_swap_b32 %0, %1" : "+v"(x),  "+v"(y));
    asm("v_permlane32_swap_b32 %0, %1" : "+v"(x2), "+v"(y2));
    union { u32 wq[4]; bf16x8 v; } uu;
    uu.wq[0] = x; uu.wq[1] = x2; uu.wq[2] = y; uu.wq[3] = y2;
    pf[f] = uu.v;
  }
  __builtin_amdgcn_s_setprio(1);
#pragma unroll
  for (int ks = 0; ks < 4; ++ks){
    o0 = mfma32(vf[ks],   pf[ks], o0);
    o1 = mfma32(vf[4+ks], pf[ks], o1);
  }
  __builtin_amdgcn_s_setprio(0);
  if (PRE) load_vfrag(vf, Vp, kvb + 64, q32, hi);    // issue now...
  __builtin_amdgcn_sched_barrier(0);                  // ...tile boundary fence
}

__global__ __launch_bounds__(256) void k_attn3(const u16* __restrict__ Q, const u16* __restrict__ Kg,
                                               const u16* __restrict__ VT, u16* __restrict__ O){
  const int tid = threadIdx.x, lane = tid & 63, w = tid >> 6;
  const int q32 = lane & 31, hi = lane >> 5;
  const int f = blockIdx.x;                    // 0..1023
  const int xcd = f & 7, slot = f >> 3;
  const int g = (slot >> 4) * 8 + xcd;         // (b,h) group, same-XCD clustering
  const int k = slot & 15;
  const int b = g >> 5, h = g & 31;
  const int qt = (w == 0) ? k : (w == 1) ? 63 - k : (w == 2) ? k + 16 : 47 - k;
  const int kvh = h >> 2;
  const u16* Qp = Q  + ((size_t)(b*NHQ  + h  ))*NL*NHD;
  const u16* Kp = Kg + ((size_t)(b*NHKV + kvh))*NL*NHD;
  const u16* Vp = VT + ((size_t)(b*NHKV + kvh))*NHD*NL;

  const int qbase = qt * 32, qrow = qbase + q32;
  bf16x8 qf[4];
#pragma unroll
  for (int ks = 0; ks < 4; ++ks)
    qf[ks] = *reinterpret_cast<const bf16x8*>(&Qp[(size_t)qrow*NHD + ks*16 + hi*8]);

  f32x16 o0 = {}, o1 = {};
  float mrun = -1e30f, lsum = 0.0f;
  const int nt = (qbase + 95) >> 6;
  const int ntm = nt - 1;                      // unmasked tiles

  bf16x8 kf0[8], kf1[8], vf[8];
  load_kfrag(kf0, Kp, 0, q32, hi);
  load_vfrag(vf,  Vp, 0, q32, hi);

  int j = 0;
#pragma unroll 1
  for (; j + 2 <= ntm; j += 2){
    attn_tile<false, true>(o0, o1, mrun, lsum, qf, kf0, kf1, vf, Kp, Vp, j<<6,     qrow, q32, hi);
    attn_tile<false, true>(o0, o1, mrun, lsum, qf, kf1, kf0, vf, Kp, Vp, (j+1)<<6, qrow, q32, hi);
  }
  if (j < ntm){
    attn_tile<false, true >(o0, o1, mrun, lsum, qf, kf0, kf1, vf, Kp, Vp, j<<6,     qrow, q32, hi);
    attn_tile<true , false>(o0, o1, mrun, lsum, qf, kf1, kf1, vf, Kp, Vp, (j+1)<<6, qrow, q32, hi);
  } else {
    attn_tile<true , false>(o0, o1, mrun, lsum, qf, kf0, kf0, vf, Kp, Vp, j<<6,     qrow, q32, hi);
  }

  float lt = lsum + __shfl_xor(lsum, 32);
  const float inv = 1.0f / lt;
  u16* Op = O + ((size_t)(b*NL + qrow))*ND + h*NHD;
#pragma unroll
  for (int md = 0; md < 2; ++md){
#pragma unroll
    for (int q4 = 0; q4 < 4; ++q4){
      ushort4 sv;
      float a0 = (md ? o1[4*q4+0] : o0[4*q4+0]) * inv;
      float a1 = (md ? o1[4*q4+1] : o0[4*q4+1]) * inv;
      float a2 = (md ? o1[4*q4+2] : o0[4*q4+2]) * inv;
      float a3 = (md ? o1[4*q4+3] : o0[4*q4+3]) * inv;
      sv.x = f2bf(a0); sv.y = f2bf(a1); sv.z = f2bf(a2); sv.w = f2bf(a3);
      *reinterpret_cast<ushort4*>(&Op[md*32 + 8*q4 + 4*hi]) = sv;
    }
  }
}

extern "C" void kernel_launch(void* const* d_in, const int* in_sizes, int n_in,
                              void* d_out, int out_size, void* d_ws, size_t ws_size,
                              hipStream_t stream){
  (void)in_sizes; (void)n_in; (void)out_size; (void)ws_size;
  const float* x   = (const float*)d_in[0];
  const int*   pos = (const int*)  d_in[1];
  const float* wq  = (const float*)d_in[2];
  const float* wk  = (const float*)d_in[3];
  const float* wv  = (const float*)d_in[4];
  const float* wo  = (const float*)d_in[5];

  char* ws = (char*)d_ws;
  size_t off = 0;
  auto alloc = [&](size_t bytes) -> void* {
    void* p = ws + off;
    off += (bytes + 255) & ~(size_t)255;
    return p;
  };
  const size_t n_x   = (size_t)NB*NL*ND;
  const size_t n_wq  = (size_t)ND*ND;
  const size_t n_wkv = (size_t)NHKV*NHD*ND;

  u16* xb    = (u16*)alloc(n_x*2);                       // reused as attn output O
  u16* wqkvb = (u16*)alloc((size_t)NQKV*ND*2);
  u16* wob   = (u16*)alloc(n_wq*2);
  u16* qkv   = (u16*)alloc((size_t)NB*NL*NQKV*2);
  u16* Qb    = (u16*)alloc((size_t)NB*NHQ*NL*NHD*2);
  u16* Kb    = (u16*)alloc((size_t)NB*NHKV*NL*NHD*2);
  u16* Vb    = (u16*)alloc((size_t)NB*NHKV*NL*NHD*2);
  u16* VTb   = (u16*)alloc((size_t)NB*NHKV*NHD*NL*2);
  float* cosT= (float*)alloc((size_t)NL*32*4);
  float* sinT= (float*)alloc((size_t)NL*32*4);

  k_cvt<<<(int)(n_x/4/256),   256, 0, stream>>>(x,  xb, (int)(n_x/4));
  k_cvt<<<(int)(n_wq/4/256),  256, 0, stream>>>(wq, wqkvb, (int)(n_wq/4));
  k_cvt<<<(int)(n_wkv/4/256), 256, 0, stream>>>(wk, wqkvb + n_wq, (int)(n_wkv/4));
  k_cvt<<<(int)(n_wkv/4/256), 256, 0, stream>>>(wv, wqkvb + n_wq + n_wkv, (int)(n_wkv/4));
  k_cvt<<<(int)(n_wq/4/256),  256, 0, stream>>>(wo, wob, (int)(n_wq/4));
  k_rope_tab<<<(NL*32)/256, 256, 0, stream>>>(pos, cosT, sinT);

  k_gemm_nt<0><<<dim3(NQKV/128, (NB*NL)/128), 256, 0, stream>>>(xb, wqkvb, qkv, NB*NL, NQKV, ND);
  k_rope_scatter<<<NB*NL, 256, 0, stream>>>(qkv, cosT, sinT, Qb, Kb, Vb);
  k_transpose<<<NB*NHKV*(NL/64), 256, 0, stream>>>(Vb, VTb);
  k_attn3<<<1024, 256, 0, stream>>>(Qb, Kb, VTb, xb);
  k_gemm_nt<1><<<dim3(ND/128, (NB*NL)/128), 256, 0, stream>>>(xb, wob, d_out, NB*NL, ND, ND);
}

// Round 7
// 255.836 us; speedup vs baseline: 1.1695x; 1.1695x over previous
//
#include <hip/hip_runtime.h>
#include <stdint.h>

typedef unsigned short u16;
typedef unsigned int   u32;
typedef __bf16 bf16_t;
typedef bf16_t bf16x8 __attribute__((ext_vector_type(8)));
typedef u16    u16x8  __attribute__((ext_vector_type(8)));
typedef float  f32x4  __attribute__((ext_vector_type(4)));
typedef float  f32x16 __attribute__((ext_vector_type(16)));

#define NB   2
#define NL   2048
#define ND   2048
#define NHQ  32
#define NHKV 8
#define NHD  64
#define NQKV 3072   // D + 2*HKV*HD
#define QSCALE 0.18033688011112042f   // 0.125 * log2(e): softmax runs in exp2 domain

__device__ __forceinline__ u16 f2bf(float x){
  union{float f;u32 u;} v; v.f = x;
  u32 r = v.u + 0x7FFFu + ((v.u >> 16) & 1u);   // RTNE
  return (u16)(r >> 16);
}
__device__ __forceinline__ float bf2f(u16 b){
  union{u32 u;float f;} v; v.u = ((u32)b) << 16; return v.f;
}

__device__ __forceinline__ float exp2_hw(float x){
#if __has_builtin(__builtin_amdgcn_exp2f)
  return __builtin_amdgcn_exp2f(x);
#else
  float r; asm("v_exp_f32 %0, %1" : "=v"(r) : "v"(x)); return r;
#endif
}

__device__ __forceinline__ void gload_lds16(const void* g, void* l){
  auto gp = reinterpret_cast<__attribute__((address_space(1))) u16*>(
      (uintptr_t)g);
  auto lp = reinterpret_cast<__attribute__((address_space(3))) u16*>(
      (uintptr_t)l);
  __builtin_amdgcn_global_load_lds(gp, lp, 16, 0, 0);
}

__device__ __forceinline__ f32x4 mfma16(bf16x8 a, bf16x8 b, f32x4 c){
  return __builtin_amdgcn_mfma_f32_16x16x32_bf16(a, b, c, 0, 0, 0);
}
__device__ __forceinline__ f32x16 mfma32(bf16x8 a, bf16x8 b, f32x16 c){
  return __builtin_amdgcn_mfma_f32_32x32x16_bf16(a, b, c, 0, 0, 0);
}
__device__ __forceinline__ u32 cvtpk(float lo, float hi){
  u32 w;
  asm("v_cvt_pk_bf16_f32 %0, %1, %2" : "=v"(w) : "v"(lo), "v"(hi));
  return w;
}

// ---------------- fp32 -> bf16 convert (vectorized) ----------------
__global__ void k_cvt(const float* __restrict__ in, u16* __restrict__ out, int n4){
  int i = blockIdx.x * blockDim.x + threadIdx.x;
  if (i >= n4) return;
  float4 f = reinterpret_cast<const float4*>(in)[i];
  ushort4 o;
  o.x = f2bf(f.x); o.y = f2bf(f.y); o.z = f2bf(f.z); o.w = f2bf(f.w);
  reinterpret_cast<ushort4*>(out)[i] = o;
}

// ---------------- RoPE cos/sin table [L][32] ----------------
__global__ void k_rope_tab(const int* __restrict__ pos, float* __restrict__ cosT,
                           float* __restrict__ sinT){
  int idx = blockIdx.x * 256 + threadIdx.x;      // 65536 total
  int l = idx >> 5, i = idx & 31;
  float p = (float)pos[l];
  float inv = __expf(-((float)i * (1.0f/32.0f)) * 9.210340371976184f); // ln(1e4)
  float fr = p * inv;
  cosT[idx] = cosf(fr);
  sinT[idx] = sinf(fr);
}

// ---------------- bf16 NT GEMM: C[M][N] = A[M][K] * B[N][K]^T ----------------
template<int WRITE_F32>
__global__ __launch_bounds__(256) void k_gemm_nt(const u16* __restrict__ A,
                                                 const u16* __restrict__ Bm,
                                                 void* __restrict__ Cp,
                                                 int M, int N, int K){
  __shared__ u16 As[128*32];
  __shared__ u16 Bs[128*32];
  const int tid = threadIdx.x;
  const int lane = tid & 63;
  const int w = tid >> 6;
  const int wr = w >> 1, wc = w & 1;
  const int tm = blockIdx.y * 128, tn = blockIdx.x * 128;
  const int lr = lane & 15, lg = lane >> 4;

  const int ca = 2*w, cb = 2*w+1;
  const u16* pa0 = A  + (size_t)(tm + ca*16 + (lane>>2))*K + (lane&3)*8;
  const u16* pa1 = A  + (size_t)(tm + cb*16 + (lane>>2))*K + (lane&3)*8;
  const u16* pb0 = Bm + (size_t)(tn + ca*16 + (lane>>2))*K + (lane&3)*8;
  const u16* pb1 = Bm + (size_t)(tn + cb*16 + (lane>>2))*K + (lane&3)*8;
  u16* la0 = &As[ca*512];
  u16* la1 = &As[cb*512];
  u16* lb0 = &Bs[ca*512];
  u16* lb1 = &Bs[cb*512];

  f32x4 acc[4][4] = {};

  const int nk = K >> 5;
  for (int kt = 0; kt < nk; ++kt){
    gload_lds16(pa0, la0);
    gload_lds16(pa1, la1);
    gload_lds16(pb0, lb0);
    gload_lds16(pb1, lb1);
    pa0 += 32; pa1 += 32; pb0 += 32; pb1 += 32;
    __syncthreads();
    bf16x8 af[4], bfr[4];
#pragma unroll
    for (int m = 0; m < 4; ++m)
      af[m] = *reinterpret_cast<const bf16x8*>(&As[(wr*64 + m*16 + lr)*32 + lg*8]);
#pragma unroll
    for (int n = 0; n < 4; ++n)
      bfr[n] = *reinterpret_cast<const bf16x8*>(&Bs[(wc*64 + n*16 + lr)*32 + lg*8]);
#pragma unroll
    for (int m = 0; m < 4; ++m)
#pragma unroll
      for (int n = 0; n < 4; ++n)
        acc[m][n] = mfma16(af[m], bfr[n], acc[m][n]);
    __syncthreads();
  }

  const int rbase = tm + wr*64 + lg*4;
  const int cbase = tn + wc*64 + lr;
#pragma unroll
  for (int m = 0; m < 4; ++m){
#pragma unroll
    for (int n = 0; n < 4; ++n){
#pragma unroll
      for (int r = 0; r < 4; ++r){
        size_t off = (size_t)(rbase + m*16 + r)*N + (cbase + n*16);
        if (WRITE_F32) ((float*)Cp)[off] = acc[m][n][r];
        else           ((u16*)Cp)[off]   = f2bf(acc[m][n][r]);
      }
    }
  }
}

// ---------------- RoPE + scatter ----------------
__global__ void k_rope_scatter(const u16* __restrict__ qkv, const float* __restrict__ cosT,
                               const float* __restrict__ sinT,
                               u16* __restrict__ Q, u16* __restrict__ Ko, u16* __restrict__ V){
  const int row = blockIdx.x;                 // b*L + l
  const int b = row >> 11, l = row & 2047;
  const int t = threadIdx.x;
#pragma unroll
  for (int it = 0; it < 6; ++it){
    int pp = t + it*256;
    u32 xin = *reinterpret_cast<const u32*>(&qkv[(size_t)row*NQKV + pp*2]);
    float x1 = bf2f((u16)(xin & 0xFFFFu));
    float x2 = bf2f((u16)(xin >> 16));
    if (pp < 1280){
      int i = pp & 31;
      float c = cosT[l*32 + i], s = sinT[l*32 + i];
      float y1 = x1*c - x2*s;
      float y2 = x1*s + x2*c;
      if (pp < 1024){
        int hh = pp >> 5, d = (pp & 31)*2;
        u32 o = (u32)f2bf(y1*QSCALE) | ((u32)f2bf(y2*QSCALE) << 16);
        *reinterpret_cast<u32*>(&Q[(((size_t)(b*NHQ + hh))*NL + l)*NHD + d]) = o;
      } else {
        int idx = pp - 1024, kvh = idx >> 5, d = (idx & 31)*2;
        u32 o = (u32)f2bf(y1) | ((u32)f2bf(y2) << 16);
        *reinterpret_cast<u32*>(&Ko[(((size_t)(b*NHKV + kvh))*NL + l)*NHD + d]) = o;
      }
    } else {
      int idx = pp - 1280, kvh = idx >> 5, d = (idx & 31)*2;
      *reinterpret_cast<u32*>(&V[(((size_t)(b*NHKV + kvh))*NL + l)*NHD + d]) = xin;
    }
  }
}

// ---------------- V[b][kvh][l][d] -> VT[b][kvh][d][l] ----------------
__global__ __launch_bounds__(256) void k_transpose(const u16* __restrict__ V, u16* __restrict__ VT){
  __shared__ u16 T[64*72];
  const int bid = blockIdx.x;
  const int slice = bid >> 5, tile = bid & 31;
  const u16* src = V  + (size_t)slice*NL*NHD + (size_t)tile*64*NHD;
  u16*       dst = VT + (size_t)slice*NHD*NL + (size_t)tile*64;
  const int t = threadIdx.x;
  {
    int r = t >> 2, c0 = (t & 3)*16;
    const u16x8* s = reinterpret_cast<const u16x8*>(src + (size_t)r*NHD + c0);
    *reinterpret_cast<u16x8*>(&T[r*72 + c0])     = s[0];
    *reinterpret_cast<u16x8*>(&T[r*72 + c0 + 8]) = s[1];
  }
  __syncthreads();
  {
    int d = t >> 2, l0 = (t & 3)*16;
    u16x8 v0, v1;
#pragma unroll
    for (int j = 0; j < 8; ++j) v0[j] = T[(l0+j)*72 + d];
#pragma unroll
    for (int j = 0; j < 8; ++j) v1[j] = T[(l0+8+j)*72 + d];
    u16* dp = dst + (size_t)d*NL + l0;
    *reinterpret_cast<u16x8*>(dp)     = v0;
    *reinterpret_cast<u16x8*>(dp + 8) = v1;
  }
}

// ---------------- causal GQA flash attention: LDS-staged lockstep ----------------
// Block = 4 waves, one (b,h). Waves own q-tiles {4m..4m+3} (near-equal trip
// counts -> <=3% lockstep idle). KV tile (64 rows) staged ONCE per block into
// LDS via global_load_lds (zero VGPR), double-buffered: stage(j+1) || compute(j),
// one __syncthreads per tile. XOR-swizzle (rule21): linear LDS dest, inverse-
// swizzled GLOBAL source, swizzled ds_read -> no 32-way bank conflict.
__device__ __forceinline__ void stage_kv(const u16* __restrict__ Kp, const u16* __restrict__ VTp,
                                         int kvb, u16* lk, u16* lv, int w, int lane){
  const char* ks = (const char*)(Kp + (size_t)kvb*NHD);     // 8KB contiguous
  const char* vs = (const char*)VTp + (size_t)kvb*2;        // 64 rows, stride NL*2
  const int o0 = w*1024 + lane*16;
#pragma unroll
  for (int i = 0; i < 2; ++i){
    int o  = o0 + i*4096;
    int sw = o ^ (((o>>7)&7)<<4);                           // inverse-swizzled source
    gload_lds16(ks + sw, (char*)lk + w*1024 + i*4096);      // LDS base wave-uniform
    int d = o>>7, c = o&127;
    gload_lds16(vs + (size_t)d*(NL*2) + (c ^ ((d&7)<<4)), (char*)lv + w*1024 + i*4096);
  }
}
__device__ __forceinline__ bf16x8 lds16(const u16* base, int row, int colb){
  return *reinterpret_cast<const bf16x8*>((const char*)base + row*128 + (colb ^ ((row&7)<<4)));
}

__global__ __launch_bounds__(256) void k_attn4(const u16* __restrict__ Q, const u16* __restrict__ Kg,
                                               const u16* __restrict__ VT, u16* __restrict__ O){
  __shared__ u16 LK[2][4096];
  __shared__ u16 LV[2][4096];
  const int tid = threadIdx.x, lane = tid & 63, w = tid >> 6;
  const int q32 = lane & 31, hi = lane >> 5;
  const int f = blockIdx.x;                    // 0..1023
  const int xcd = f & 7, slot = f >> 3;
  const int g = (slot >> 4) * 8 + xcd;         // (b,h), same-XCD clustering
  const int m = 15 - (slot & 15);              // long blocks first
  const int b = g >> 5, h = g & 31;
  const int qt = 4*m + w;
  const int kvh = h >> 2;
  const u16* Qp  = Q  + ((size_t)(b*NHQ  + h  ))*NL*NHD;
  const u16* Kp  = Kg + ((size_t)(b*NHKV + kvh))*NL*NHD;
  const u16* VTp = VT + ((size_t)(b*NHKV + kvh))*NHD*NL;

  const int qbase = qt * 32, qrow = qbase + q32;
  const int ntw   = (qbase + 95) >> 6;                 // this wave's trip count
  const int ntmax = ((4*m+3)*32 + 95) >> 6;            // block trip count

  bf16x8 qf[4];
#pragma unroll
  for (int ks = 0; ks < 4; ++ks)
    qf[ks] = *reinterpret_cast<const bf16x8*>(&Qp[(size_t)qrow*NHD + ks*16 + hi*8]);

  f32x16 o0 = {}, o1 = {};
  float mrun = -1e30f, lsum = 0.0f;

  stage_kv(Kp, VTp, 0, LK[0], LV[0], w, lane);
  __syncthreads();

#pragma unroll 1
  for (int j = 0; j < ntmax; ++j){
    const int cur = j & 1;
    const u16* lk = LK[cur];
    const u16* lv = LV[cur];
    if (j + 1 < ntmax)
      stage_kv(Kp, VTp, (j+1) << 6, LK[cur^1], LV[cur^1], w, lane);

    if (j < ntw){
      const int kvb = j << 6;
      // ---- frags from LDS ----
      bf16x8 kf[8], vf[8];
#pragma unroll
      for (int ks = 0; ks < 4; ++ks){
        kf[ks]   = lds16(lk, q32,      ks*32 + hi*16);
        kf[4+ks] = lds16(lk, 32 + q32, ks*32 + hi*16);
        vf[ks]   = lds16(lv, q32,      ks*32 + hi*16);
        vf[4+ks] = lds16(lv, 32 + q32, ks*32 + hi*16);
      }
      // ---- S^T = K.Q^T ----
      f32x16 s0 = {}, s1 = {};
      __builtin_amdgcn_s_setprio(1);
#pragma unroll
      for (int ks = 0; ks < 4; ++ks){
        s0 = mfma32(kf[ks],   qf[ks], s0);
        s1 = mfma32(kf[4+ks], qf[ks], s1);
      }
      __builtin_amdgcn_s_setprio(0);
      float pv[32];
#pragma unroll
      for (int r = 0; r < 16; ++r){ pv[r] = s0[r]; pv[16+r] = s1[r]; }
      if (j == ntw - 1){                       // causal mask, edge tile
#pragma unroll
        for (int r = 0; r < 16; ++r){
          const int kl = (r&3) + 8*(r>>2) + 4*hi;
          pv[r]    = (kvb + kl      <= qrow) ? pv[r]    : -1e30f;
          pv[16+r] = (kvb + 32 + kl <= qrow) ? pv[16+r] : -1e30f;
        }
      }
      // ---- row max ----
      float t[8];
#pragma unroll
      for (int r = 0; r < 8; ++r)  t[r] = fmaxf(fmaxf(pv[r], pv[r+8]), pv[r+16]);
#pragma unroll
      for (int r = 0; r < 4; ++r)  t[r] = fmaxf(fmaxf(t[r], t[r+4]), pv[24+r]);
      t[0] = fmaxf(fmaxf(t[0], t[1]), fmaxf(t[2], t[3]));
      const float mnew = fmaxf(t[0], __shfl_xor(t[0], 32));
      if (__any(mnew - mrun > 8.0f)){          // defer-max (T13)
        const float mupd = fmaxf(mrun, mnew);
        const float c = exp2_hw(mrun - mupd);
        lsum *= c;
#pragma unroll
        for (int r = 0; r < 16; ++r){ o0[r] *= c; o1[r] *= c; }
        mrun = mupd;
      }
      float p[32];
#pragma unroll
      for (int r = 0; r < 32; ++r) p[r] = exp2_hw(pv[r] - mrun);
      float u[16];
#pragma unroll
      for (int r = 0; r < 16; ++r) u[r] = p[r] + p[16+r];
#pragma unroll
      for (int r = 0; r < 8; ++r)  u[r] += u[r+8];
#pragma unroll
      for (int r = 0; r < 4; ++r)  u[r] += u[r+4];
      lsum += (u[0]+u[1]) + (u[2]+u[3]);
      // ---- P -> bf16 B-frags ----
      u32 wds[16];
#pragma unroll
      for (int i = 0; i < 16; ++i) wds[i] = cvtpk(p[2*i], p[2*i+1]);
      bf16x8 pf[4];
#pragma unroll
      for (int fi = 0; fi < 4; ++fi){
        u32 x  = wds[4*fi+0], y  = wds[4*fi+2];
        u32 x2 = wds[4*fi+1], y2 = wds[4*fi+3];
        asm("v_permlane32_swap_b32 %0, %1" : "+v"(x),  "+v"(y));
        asm("v_permlane32_swap_b32 %0, %1" : "+v"(x2), "+v"(y2));
        union { u32 wq[4]; bf16x8 v; } uu;
        uu.wq[0] = x; uu.wq[1] = x2; uu.wq[2] = y; uu.wq[3] = y2;
        pf[fi] = uu.v;
      }
      // ---- O^T += V^T.P^T ----
      __builtin_amdgcn_s_setprio(1);
#pragma unroll
      for (int ks = 0; ks < 4; ++ks){
        o0 = mfma32(vf[ks],   pf[ks], o0);
        o1 = mfma32(vf[4+ks], pf[ks], o1);
      }
      __builtin_amdgcn_s_setprio(0);
    }
    __syncthreads();                           // stage(j+1) done + all reads of buf done
  }

  float lt = lsum + __shfl_xor(lsum, 32);
  const float inv = 1.0f / lt;
  u16* Op = O + ((size_t)(b*NL + qrow))*ND + h*NHD;
#pragma unroll
  for (int md = 0; md < 2; ++md){
#pragma unroll
    for (int q4 = 0; q4 < 4; ++q4){
      ushort4 sv;
      float a0 = (md ? o1[4*q4+0] : o0[4*q4+0]) * inv;
      float a1 = (md ? o1[4*q4+1] : o0[4*q4+1]) * inv;
      float a2 = (md ? o1[4*q4+2] : o0[4*q4+2]) * inv;
      float a3 = (md ? o1[4*q4+3] : o0[4*q4+3]) * inv;
      sv.x = f2bf(a0); sv.y = f2bf(a1); sv.z = f2bf(a2); sv.w = f2bf(a3);
      *reinterpret_cast<ushort4*>(&Op[md*32 + 8*q4 + 4*hi]) = sv;
    }
  }
}

extern "C" void kernel_launch(void* const* d_in, const int* in_sizes, int n_in,
                              void* d_out, int out_size, void* d_ws, size_t ws_size,
                              hipStream_t stream){
  (void)in_sizes; (void)n_in; (void)out_size; (void)ws_size;
  const float* x   = (const float*)d_in[0];
  const int*   pos = (const int*)  d_in[1];
  const float* wq  = (const float*)d_in[2];
  const float* wk  = (const float*)d_in[3];
  const float* wv  = (const float*)d_in[4];
  const float* wo  = (const float*)d_in[5];

  char* ws = (char*)d_ws;
  size_t off = 0;
  auto alloc = [&](size_t bytes) -> void* {
    void* p = ws + off;
    off += (bytes + 255) & ~(size_t)255;
    return p;
  };
  const size_t n_x   = (size_t)NB*NL*ND;
  const size_t n_wq  = (size_t)ND*ND;
  const size_t n_wkv = (size_t)NHKV*NHD*ND;

  u16* xb    = (u16*)alloc(n_x*2);                       // reused as attn output O
  u16* wqkvb = (u16*)alloc((size_t)NQKV*ND*2);
  u16* wob   = (u16*)alloc(n_wq*2);
  u16* qkv   = (u16*)alloc((size_t)NB*NL*NQKV*2);
  u16* Qb    = (u16*)alloc((size_t)NB*NHQ*NL*NHD*2);
  u16* Kb    = (u16*)alloc((size_t)NB*NHKV*NL*NHD*2);
  u16* Vb    = (u16*)alloc((size_t)NB*NHKV*NL*NHD*2);
  u16* VTb   = (u16*)alloc((size_t)NB*NHKV*NHD*NL*2);
  float* cosT= (float*)alloc((size_t)NL*32*4);
  float* sinT= (float*)alloc((size_t)NL*32*4);

  k_cvt<<<(int)(n_x/4/256),   256, 0, stream>>>(x,  xb, (int)(n_x/4));
  k_cvt<<<(int)(n_wq/4/256),  256, 0, stream>>>(wq, wqkvb, (int)(n_wq/4));
  k_cvt<<<(int)(n_wkv/4/256), 256, 0, stream>>>(wk, wqkvb + n_wq, (int)(n_wkv/4));
  k_cvt<<<(int)(n_wkv/4/256), 256, 0, stream>>>(wv, wqkvb + n_wq + n_wkv, (int)(n_wkv/4));
  k_cvt<<<(int)(n_wq/4/256),  256, 0, stream>>>(wo, wob, (int)(n_wq/4));
  k_rope_tab<<<(NL*32)/256, 256, 0, stream>>>(pos, cosT, sinT);

  k_gemm_nt<0><<<dim3(NQKV/128, (NB*NL)/128), 256, 0, stream>>>(xb, wqkvb, qkv, NB*NL, NQKV, ND);
  k_rope_scatter<<<NB*NL, 256, 0, stream>>>(qkv, cosT, sinT, Qb, Kb, Vb);
  k_transpose<<<NB*NHKV*(NL/64), 256, 0, stream>>>(Vb, VTb);
  k_attn4<<<1024, 256, 0, stream>>>(Qb, Kb, VTb, xb);
  k_gemm_nt<1><<<dim3(ND/128, (NB*NL)/128), 256, 0, stream>>>(xb, wob, d_out, NB*NL, ND, ND);
}